// Round 12
// baseline (145.338 us; speedup 1.0000x reference)
//
#include <hip/hip_runtime.h>
#include <cstdint>

#define NSTARS 4096
#define NDIC   4096
#define NFEAT  16
#define NPIX   65536    // 256*256
#define BATCH  2048
#define RPB    8        // rows per k_inter block
#define BPB    256      // batch rows per k_opd block (R8 value — proven best)

using f32x4 = __attribute__((ext_vector_type(4))) float;

// ---------------------------------------------------------------------------
// Kernel A v6: R8 structure, d-range split in two -> 512 blocks = 2 blocks/CU
// (2 waves/SIMD instead of 1). Same total VMEM instr count (6.3M); pure
// occupancy/stall-coverage test. Partials [2][BATCH][16] -> d_ws; k_opd sums.
// ---------------------------------------------------------------------------
__global__ __launch_bounds__(256) void k_inter(
    const float*  __restrict__ positions,   // [BATCH,2]
    const float2* __restrict__ obs,         // [NSTARS] as float2
    const float*  __restrict__ spatial,     // [NSTARS,NDIC]
    const float*  __restrict__ alpha,       // [NDIC,NFEAT]
    float*        __restrict__ partial)     // [2][BATCH][NFEAT]
{
    __shared__ int   s_idx[RPB];
    __shared__ float s_red[4 * RPB * NFEAT];   // [wave][row][feat]

    const int tid  = threadIdx.x;
    const int lane = tid & 63;
    const int wave = tid >> 6;
    const int seg  = blockIdx.x & 1;           // d-half: [0,2048) or [2048,4096)
    const int b0   = (blockIdx.x >> 1) * RPB;

    if (tid < RPB) s_idx[tid] = 0x7FFFFFFF;
    __syncthreads();

    // lookup: first flat-equal element row-major -> min star with x OR y match
    float px[RPB], py[RPB];
    #pragma unroll
    for (int b = 0; b < RPB; ++b) {
        px[b] = positions[(b0 + b) * 2 + 0];
        py[b] = positions[(b0 + b) * 2 + 1];
    }
    for (int s = tid; s < NSTARS; s += 256) {
        float2 o = obs[s];
        #pragma unroll
        for (int b = 0; b < RPB; ++b) {
            if (px[b] == o.x || py[b] == o.y) atomicMin(&s_idx[b], s);
        }
    }
    __syncthreads();

    int idx[RPB];
    #pragma unroll
    for (int b = 0; b < RPB; ++b) {
        int v = s_idx[b];
        idx[b] = (v == 0x7FFFFFFF) ? 0 : v;
    }

    float acc[RPB][NFEAT];
    #pragma unroll
    for (int b = 0; b < RPB; ++b)
        #pragma unroll
        for (int f = 0; f < NFEAT; ++f) acc[b][f] = 0.0f;

    const float4* alpha4 = (const float4*)alpha;

    #pragma unroll
    for (int step = 0; step < 2; ++step) {
        const int d0 = seg * 2048 + step * 1024 + tid * 4;
        float4 v[RPB];
        #pragma unroll
        for (int b = 0; b < RPB; ++b)
            v[b] = *(const float4*)(spatial + (size_t)idx[b] * NDIC + d0);

        #pragma unroll
        for (int k = 0; k < 4; ++k) {
            const float4 a0 = alpha4[(size_t)(d0 + k) * 4 + 0];
            const float4 a1 = alpha4[(size_t)(d0 + k) * 4 + 1];
            const float4 a2 = alpha4[(size_t)(d0 + k) * 4 + 2];
            const float4 a3 = alpha4[(size_t)(d0 + k) * 4 + 3];
            #pragma unroll
            for (int b = 0; b < RPB; ++b) {
                const float vb = (&v[b].x)[k];
                acc[b][0]  += vb * a0.x;  acc[b][1]  += vb * a0.y;
                acc[b][2]  += vb * a0.z;  acc[b][3]  += vb * a0.w;
                acc[b][4]  += vb * a1.x;  acc[b][5]  += vb * a1.y;
                acc[b][6]  += vb * a1.z;  acc[b][7]  += vb * a1.w;
                acc[b][8]  += vb * a2.x;  acc[b][9]  += vb * a2.y;
                acc[b][10] += vb * a2.z;  acc[b][11] += vb * a2.w;
                acc[b][12] += vb * a3.x;  acc[b][13] += vb * a3.y;
                acc[b][14] += vb * a3.z;  acc[b][15] += vb * a3.w;
            }
        }
    }

    // 64-lane butterfly over 128 (row,feat) values
    #pragma unroll
    for (int off = 1; off < 64; off <<= 1)
        #pragma unroll
        for (int b = 0; b < RPB; ++b)
            #pragma unroll
            for (int f = 0; f < NFEAT; ++f)
                acc[b][f] += __shfl_xor(acc[b][f], off);

    if (lane == 0) {
        #pragma unroll
        for (int b = 0; b < RPB; ++b)
            #pragma unroll
            for (int f = 0; f < NFEAT; f += 4)
                *(float4*)&s_red[(wave * RPB + b) * NFEAT + f] =
                    make_float4(acc[b][f], acc[b][f+1], acc[b][f+2], acc[b][f+3]);
    }
    __syncthreads();

    if (tid < RPB * NFEAT) {            // 128 threads
        const int r = tid >> 4, f = tid & 15;
        float x = s_red[(0 * RPB + r) * NFEAT + f]
                + s_red[(1 * RPB + r) * NFEAT + f]
                + s_red[(2 * RPB + r) * NFEAT + f]
                + s_red[(3 * RPB + r) * NFEAT + f];
        partial[((size_t)seg * BATCH + (b0 + r)) * NFEAT + f] = x;
    }
}

// ---------------------------------------------------------------------------
// Kernel B: exact R8 structure (BPB=256, 512 blocks, scalar uniform w-loads,
// nt store bursts); w = partial[0][row] + partial[1][row] (scalar pipe).
// ---------------------------------------------------------------------------
__global__ __launch_bounds__(256) void k_opd(
    const float* __restrict__ part,     // [2][BATCH][NFEAT]
    const f32x4* __restrict__ S4,       // [NFEAT, NPIX/4]
    f32x4*       __restrict__ out4)     // [BATCH, NPIX/4]
{
    const int tid   = threadIdx.x;
    const int chunk = blockIdx.x & 63;       // pixel chunk (1024 px)
    const int bg    = blockIdx.x >> 6;       // batch group of BPB rows (0..7)
    const int p4    = chunk * 256 + tid;     // float4 index in [0, 16384)

    f32x4 s[NFEAT];
    #pragma unroll
    for (int f = 0; f < NFEAT; ++f)
        s[f] = S4[(size_t)f * (NPIX / 4) + p4];

    const float* w0 = part + (size_t)bg * BPB * NFEAT;                 // seg0
    const float* w1 = w0 + (size_t)BATCH * NFEAT;                      // seg1
    f32x4* o = out4 + (size_t)bg * BPB * (NPIX / 4) + p4;

    for (int g = 0; g < BPB / 4; ++g) {
        f32x4 acc[4];
        #pragma unroll
        for (int b = 0; b < 4; ++b) {
            const size_t ro = (size_t)(g * 4 + b) * NFEAT;
            const float* wa = w0 + ro;      // uniform addr -> s_load
            const float* wb = w1 + ro;
            float wf[NFEAT];
            #pragma unroll
            for (int f = 0; f < NFEAT; ++f) wf[f] = wa[f] + wb[f];
            f32x4 a = s[0] * wf[0];
            a += s[1]  * wf[1];   a += s[2]  * wf[2];   a += s[3]  * wf[3];
            a += s[4]  * wf[4];   a += s[5]  * wf[5];   a += s[6]  * wf[6];
            a += s[7]  * wf[7];   a += s[8]  * wf[8];   a += s[9]  * wf[9];
            a += s[10] * wf[10];  a += s[11] * wf[11];  a += s[12] * wf[12];
            a += s[13] * wf[13];  a += s[14] * wf[14];  a += s[15] * wf[15];
            acc[b] = a;
        }
        #pragma unroll
        for (int b = 0; b < 4; ++b)
            __builtin_nontemporal_store(acc[b],
                o + (size_t)(g * 4 + b) * (NPIX / 4));
    }
}

extern "C" void kernel_launch(void* const* d_in, const int* in_sizes, int n_in,
                              void* d_out, int out_size, void* d_ws, size_t ws_size,
                              hipStream_t stream) {
    const float*  positions = (const float*)d_in[0];   // [2048,2]
    const float2* obs       = (const float2*)d_in[1];  // [4096,2]
    const float*  spatial   = (const float*)d_in[2];   // [4096,4096]
    const float*  alpha     = (const float*)d_in[3];   // [4096,16]
    const f32x4*  S4        = (const f32x4*)d_in[4];   // [16,256,256]
    f32x4*        out       = (f32x4*)d_out;           // [2048,256,256]
    float*        partial   = (float*)d_ws;            // [2][2048][16] scratch

    k_inter<<<(BATCH / RPB) * 2, 256, 0, stream>>>(positions, obs, spatial, alpha, partial);
    k_opd<<<(NPIX / 1024) * (BATCH / BPB), 256, 0, stream>>>(
        partial, S4, out);
}

// Round 13
// 137.528 us; speedup vs baseline: 1.0568x; 1.0568x over previous
//
#include <hip/hip_runtime.h>
#include <cstdint>

#define NSTARS 4096
#define NDIC   4096
#define NFEAT  16
#define NPIX   65536    // 256*256
#define BATCH  2048
#define RPB    8        // rows per k_inter block
#define BPB    256      // batch rows per k_opd block (proven local optimum)

using f32x4 = __attribute__((ext_vector_type(4))) float;

// ---------------------------------------------------------------------------
// Kernel A: exact R8 k_inter (verified best). 256 blocks x 256 threads,
// RPB=8 rows share each alpha load (6.3M total VMEM instrs).
// ---------------------------------------------------------------------------
__global__ __launch_bounds__(256) void k_inter(
    const float*  __restrict__ positions,   // [BATCH,2]
    const float2* __restrict__ obs,         // [NSTARS] as float2
    const float*  __restrict__ spatial,     // [NSTARS,NDIC]
    const float*  __restrict__ alpha,       // [NDIC,NFEAT]
    float*        __restrict__ inter)       // [BATCH,NFEAT] out
{
    __shared__ int   s_idx[RPB];
    __shared__ float s_red[4 * RPB * NFEAT];   // [wave][row][feat]

    const int tid  = threadIdx.x;
    const int lane = tid & 63;
    const int wave = tid >> 6;
    const int b0   = blockIdx.x * RPB;

    if (tid < RPB) s_idx[tid] = 0x7FFFFFFF;
    __syncthreads();

    // lookup: first flat-equal element row-major -> min star with x OR y match
    float px[RPB], py[RPB];
    #pragma unroll
    for (int b = 0; b < RPB; ++b) {
        px[b] = positions[(b0 + b) * 2 + 0];
        py[b] = positions[(b0 + b) * 2 + 1];
    }
    for (int s = tid; s < NSTARS; s += 256) {
        float2 o = obs[s];
        #pragma unroll
        for (int b = 0; b < RPB; ++b) {
            if (px[b] == o.x || py[b] == o.y) atomicMin(&s_idx[b], s);
        }
    }
    __syncthreads();

    int idx[RPB];
    #pragma unroll
    for (int b = 0; b < RPB; ++b) {
        int v = s_idx[b];
        idx[b] = (v == 0x7FFFFFFF) ? 0 : v;
    }

    float acc[RPB][NFEAT];
    #pragma unroll
    for (int b = 0; b < RPB; ++b)
        #pragma unroll
        for (int f = 0; f < NFEAT; ++f) acc[b][f] = 0.0f;

    const float4* alpha4 = (const float4*)alpha;

    #pragma unroll
    for (int step = 0; step < 4; ++step) {
        const int d0 = tid * 4 + step * 1024;
        float4 v[RPB];
        #pragma unroll
        for (int b = 0; b < RPB; ++b)
            v[b] = *(const float4*)(spatial + (size_t)idx[b] * NDIC + d0);

        #pragma unroll
        for (int k = 0; k < 4; ++k) {
            const float4 a0 = alpha4[(size_t)(d0 + k) * 4 + 0];
            const float4 a1 = alpha4[(size_t)(d0 + k) * 4 + 1];
            const float4 a2 = alpha4[(size_t)(d0 + k) * 4 + 2];
            const float4 a3 = alpha4[(size_t)(d0 + k) * 4 + 3];
            #pragma unroll
            for (int b = 0; b < RPB; ++b) {
                const float vb = (&v[b].x)[k];
                acc[b][0]  += vb * a0.x;  acc[b][1]  += vb * a0.y;
                acc[b][2]  += vb * a0.z;  acc[b][3]  += vb * a0.w;
                acc[b][4]  += vb * a1.x;  acc[b][5]  += vb * a1.y;
                acc[b][6]  += vb * a1.z;  acc[b][7]  += vb * a1.w;
                acc[b][8]  += vb * a2.x;  acc[b][9]  += vb * a2.y;
                acc[b][10] += vb * a2.z;  acc[b][11] += vb * a2.w;
                acc[b][12] += vb * a3.x;  acc[b][13] += vb * a3.y;
                acc[b][14] += vb * a3.z;  acc[b][15] += vb * a3.w;
            }
        }
    }

    // 64-lane butterfly over 128 (row,feat) values
    #pragma unroll
    for (int off = 1; off < 64; off <<= 1)
        #pragma unroll
        for (int b = 0; b < RPB; ++b)
            #pragma unroll
            for (int f = 0; f < NFEAT; ++f)
                acc[b][f] += __shfl_xor(acc[b][f], off);

    if (lane == 0) {
        #pragma unroll
        for (int b = 0; b < RPB; ++b)
            #pragma unroll
            for (int f = 0; f < NFEAT; f += 4)
                *(float4*)&s_red[(wave * RPB + b) * NFEAT + f] =
                    make_float4(acc[b][f], acc[b][f+1], acc[b][f+2], acc[b][f+3]);
    }
    __syncthreads();

    if (tid < RPB * NFEAT) {            // 128 threads
        const int r = tid >> 4, f = tid & 15;
        float x = s_red[(0 * RPB + r) * NFEAT + f]
                + s_red[(1 * RPB + r) * NFEAT + f]
                + s_red[(2 * RPB + r) * NFEAT + f]
                + s_red[(3 * RPB + r) * NFEAT + f];
        inter[(size_t)(b0 + r) * NFEAT + f] = x;
    }
}

// ---------------------------------------------------------------------------
// Kernel B v8: R8 structure (BPB=256, scalar uniform w, nt bursts) with ONE
// change: software-pipelined w s_loads. Two named SGPR buffers (wA/wB, 32
// floats each, rule-#20 static indexing); group g+1's scalar loads issue
// BEFORE group g's FMA+store block, hiding the ~200-500cy K$/L2 wait under
// the previous group's compute+stores.
// ---------------------------------------------------------------------------
__global__ __launch_bounds__(256) void k_opd(
    const float* __restrict__ interw,   // [BATCH, NFEAT]
    const f32x4* __restrict__ S4,       // [NFEAT, NPIX/4]
    f32x4*       __restrict__ out4)     // [BATCH, NPIX/4]
{
    const int tid   = threadIdx.x;
    const int chunk = blockIdx.x & 63;       // pixel chunk (1024 px)
    const int bg    = blockIdx.x >> 6;       // batch group of BPB rows (0..7)
    const int p4    = chunk * 256 + tid;     // float4 index in [0, 16384)

    f32x4 s[NFEAT];
    #pragma unroll
    for (int f = 0; f < NFEAT; ++f)
        s[f] = S4[(size_t)f * (NPIX / 4) + p4];

    const float* w = interw + (size_t)bg * BPB * NFEAT;   // block-uniform
    f32x4* o = out4 + (size_t)bg * BPB * (NPIX / 4) + p4;

    float wA[2][NFEAT], wB[2][NFEAT];

    // prologue: rows 0,1 -> wA
    #pragma unroll
    for (int r = 0; r < 2; ++r)
        #pragma unroll
        for (int f = 0; f < NFEAT; ++f)
            wA[r][f] = w[(size_t)r * NFEAT + f];

    // 128 two-row groups, processed as 64 A/B pairs
    for (int g = 0; g < BPB / 2; g += 2) {
        // --- iteration A: prefetch group g+1 -> wB, compute with wA ---
        {
            const int rn = (g + 1) * 2;          // always < BPB here
            #pragma unroll
            for (int r = 0; r < 2; ++r)
                #pragma unroll
                for (int f = 0; f < NFEAT; ++f)
                    wB[r][f] = w[(size_t)(rn + r) * NFEAT + f];

            f32x4 acc[2];
            #pragma unroll
            for (int r = 0; r < 2; ++r) {
                const float* wf = wA[r];
                f32x4 a = s[0] * wf[0];
                a += s[1]  * wf[1];   a += s[2]  * wf[2];   a += s[3]  * wf[3];
                a += s[4]  * wf[4];   a += s[5]  * wf[5];   a += s[6]  * wf[6];
                a += s[7]  * wf[7];   a += s[8]  * wf[8];   a += s[9]  * wf[9];
                a += s[10] * wf[10];  a += s[11] * wf[11];  a += s[12] * wf[12];
                a += s[13] * wf[13];  a += s[14] * wf[14];  a += s[15] * wf[15];
                acc[r] = a;
            }
            #pragma unroll
            for (int r = 0; r < 2; ++r)
                __builtin_nontemporal_store(acc[r],
                    o + (size_t)(g * 2 + r) * (NPIX / 4));
        }
        // --- iteration B: prefetch group g+2 -> wA (guarded), compute with wB ---
        {
            const int rn = (g + 2) * 2;
            if (g + 2 < BPB / 2) {
                #pragma unroll
                for (int r = 0; r < 2; ++r)
                    #pragma unroll
                    for (int f = 0; f < NFEAT; ++f)
                        wA[r][f] = w[(size_t)(rn + r) * NFEAT + f];
            }

            f32x4 acc[2];
            #pragma unroll
            for (int r = 0; r < 2; ++r) {
                const float* wf = wB[r];
                f32x4 a = s[0] * wf[0];
                a += s[1]  * wf[1];   a += s[2]  * wf[2];   a += s[3]  * wf[3];
                a += s[4]  * wf[4];   a += s[5]  * wf[5];   a += s[6]  * wf[6];
                a += s[7]  * wf[7];   a += s[8]  * wf[8];   a += s[9]  * wf[9];
                a += s[10] * wf[10];  a += s[11] * wf[11];  a += s[12] * wf[12];
                a += s[13] * wf[13];  a += s[14] * wf[14];  a += s[15] * wf[15];
                acc[r] = a;
            }
            #pragma unroll
            for (int r = 0; r < 2; ++r)
                __builtin_nontemporal_store(acc[r],
                    o + (size_t)((g + 1) * 2 + r) * (NPIX / 4));
        }
    }
}

extern "C" void kernel_launch(void* const* d_in, const int* in_sizes, int n_in,
                              void* d_out, int out_size, void* d_ws, size_t ws_size,
                              hipStream_t stream) {
    const float*  positions = (const float*)d_in[0];   // [2048,2]
    const float2* obs       = (const float2*)d_in[1];  // [4096,2]
    const float*  spatial   = (const float*)d_in[2];   // [4096,4096]
    const float*  alpha     = (const float*)d_in[3];   // [4096,16]
    const f32x4*  S4        = (const f32x4*)d_in[4];   // [16,256,256]
    f32x4*        out       = (f32x4*)d_out;           // [2048,256,256]
    float*        inter     = (float*)d_ws;            // [2048,16] scratch

    k_inter<<<BATCH / RPB, 256, 0, stream>>>(positions, obs, spatial, alpha, inter);
    k_opd<<<(NPIX / 1024) * (BATCH / BPB), 256, 0, stream>>>(
        inter, S4, out);
}

// Round 14
// 131.577 us; speedup vs baseline: 1.1046x; 1.0452x over previous
//
#include <hip/hip_runtime.h>
#include <cstdint>

#define NSTARS 4096
#define NDIC   4096
#define NFEAT  16
#define NPIX   65536    // 256*256
#define BATCH  2048
#define RPB    8        // rows per k_inter block
#define BPB    256      // batch rows per k_opd block

using f32x4 = __attribute__((ext_vector_type(4))) float;

// ---------------------------------------------------------------------------
// FINAL = exact R8 (verified 131.9 us; local optimum in 8 tested directions).
// k_inter: 256 blocks x 256 threads, RPB=8 rows amortize each alpha load
//          (96 VMEM instrs/thread = provable floor for this blocking).
// k_opd:   BPB=256, 512 blocks (2/CU), block-uniform scalar w-loads
//          (s_load, scalar pipe), nt store bursts (beats cached stores by
//          18us -- R5); BPB 128/512, LDS-w, and sw-pipelined-w all regressed.
// ---------------------------------------------------------------------------
__global__ __launch_bounds__(256) void k_inter(
    const float*  __restrict__ positions,   // [BATCH,2]
    const float2* __restrict__ obs,         // [NSTARS] as float2
    const float*  __restrict__ spatial,     // [NSTARS,NDIC]
    const float*  __restrict__ alpha,       // [NDIC,NFEAT]
    float*        __restrict__ inter)       // [BATCH,NFEAT] out
{
    __shared__ int   s_idx[RPB];
    __shared__ float s_red[4 * RPB * NFEAT];   // [wave][row][feat]

    const int tid  = threadIdx.x;
    const int lane = tid & 63;
    const int wave = tid >> 6;
    const int b0   = blockIdx.x * RPB;

    if (tid < RPB) s_idx[tid] = 0x7FFFFFFF;
    __syncthreads();

    // lookup: first flat-equal element row-major -> min star with x OR y match
    float px[RPB], py[RPB];
    #pragma unroll
    for (int b = 0; b < RPB; ++b) {
        px[b] = positions[(b0 + b) * 2 + 0];
        py[b] = positions[(b0 + b) * 2 + 1];
    }
    for (int s = tid; s < NSTARS; s += 256) {
        float2 o = obs[s];
        #pragma unroll
        for (int b = 0; b < RPB; ++b) {
            if (px[b] == o.x || py[b] == o.y) atomicMin(&s_idx[b], s);
        }
    }
    __syncthreads();

    int idx[RPB];
    #pragma unroll
    for (int b = 0; b < RPB; ++b) {
        int v = s_idx[b];
        idx[b] = (v == 0x7FFFFFFF) ? 0 : v;
    }

    float acc[RPB][NFEAT];
    #pragma unroll
    for (int b = 0; b < RPB; ++b)
        #pragma unroll
        for (int f = 0; f < NFEAT; ++f) acc[b][f] = 0.0f;

    const float4* alpha4 = (const float4*)alpha;

    #pragma unroll
    for (int step = 0; step < 4; ++step) {
        const int d0 = tid * 4 + step * 1024;
        float4 v[RPB];
        #pragma unroll
        for (int b = 0; b < RPB; ++b)
            v[b] = *(const float4*)(spatial + (size_t)idx[b] * NDIC + d0);

        #pragma unroll
        for (int k = 0; k < 4; ++k) {
            const float4 a0 = alpha4[(size_t)(d0 + k) * 4 + 0];
            const float4 a1 = alpha4[(size_t)(d0 + k) * 4 + 1];
            const float4 a2 = alpha4[(size_t)(d0 + k) * 4 + 2];
            const float4 a3 = alpha4[(size_t)(d0 + k) * 4 + 3];
            #pragma unroll
            for (int b = 0; b < RPB; ++b) {
                const float vb = (&v[b].x)[k];
                acc[b][0]  += vb * a0.x;  acc[b][1]  += vb * a0.y;
                acc[b][2]  += vb * a0.z;  acc[b][3]  += vb * a0.w;
                acc[b][4]  += vb * a1.x;  acc[b][5]  += vb * a1.y;
                acc[b][6]  += vb * a1.z;  acc[b][7]  += vb * a1.w;
                acc[b][8]  += vb * a2.x;  acc[b][9]  += vb * a2.y;
                acc[b][10] += vb * a2.z;  acc[b][11] += vb * a2.w;
                acc[b][12] += vb * a3.x;  acc[b][13] += vb * a3.y;
                acc[b][14] += vb * a3.z;  acc[b][15] += vb * a3.w;
            }
        }
    }

    // 64-lane butterfly over 128 (row,feat) values
    #pragma unroll
    for (int off = 1; off < 64; off <<= 1)
        #pragma unroll
        for (int b = 0; b < RPB; ++b)
            #pragma unroll
            for (int f = 0; f < NFEAT; ++f)
                acc[b][f] += __shfl_xor(acc[b][f], off);

    if (lane == 0) {
        #pragma unroll
        for (int b = 0; b < RPB; ++b)
            #pragma unroll
            for (int f = 0; f < NFEAT; f += 4)
                *(float4*)&s_red[(wave * RPB + b) * NFEAT + f] =
                    make_float4(acc[b][f], acc[b][f+1], acc[b][f+2], acc[b][f+3]);
    }
    __syncthreads();

    if (tid < RPB * NFEAT) {            // 128 threads
        const int r = tid >> 4, f = tid & 15;
        float x = s_red[(0 * RPB + r) * NFEAT + f]
                + s_red[(1 * RPB + r) * NFEAT + f]
                + s_red[(2 * RPB + r) * NFEAT + f]
                + s_red[(3 * RPB + r) * NFEAT + f];
        inter[(size_t)(b0 + r) * NFEAT + f] = x;
    }
}

__global__ __launch_bounds__(256) void k_opd(
    const float* __restrict__ interw,   // [BATCH, NFEAT]
    const f32x4* __restrict__ S4,       // [NFEAT, NPIX/4]
    f32x4*       __restrict__ out4)     // [BATCH, NPIX/4]
{
    const int tid   = threadIdx.x;
    const int chunk = blockIdx.x & 63;       // pixel chunk (1024 px)
    const int bg    = blockIdx.x >> 6;       // batch group of BPB rows (0..7)
    const int p4    = chunk * 256 + tid;     // float4 index in [0, 16384)

    f32x4 s[NFEAT];
    #pragma unroll
    for (int f = 0; f < NFEAT; ++f)
        s[f] = S4[(size_t)f * (NPIX / 4) + p4];

    const float* w = interw + (size_t)bg * BPB * NFEAT;   // block-uniform
    f32x4* o = out4 + (size_t)bg * BPB * (NPIX / 4) + p4;

    for (int g = 0; g < BPB / 4; ++g) {
        f32x4 acc[4];
        #pragma unroll
        for (int b = 0; b < 4; ++b) {
            const float* wr = w + (size_t)(g * 4 + b) * NFEAT;  // uniform addr
            f32x4 a = s[0] * wr[0];
            a += s[1]  * wr[1];   a += s[2]  * wr[2];   a += s[3]  * wr[3];
            a += s[4]  * wr[4];   a += s[5]  * wr[5];   a += s[6]  * wr[6];
            a += s[7]  * wr[7];   a += s[8]  * wr[8];   a += s[9]  * wr[9];
            a += s[10] * wr[10];  a += s[11] * wr[11];  a += s[12] * wr[12];
            a += s[13] * wr[13];  a += s[14] * wr[14];  a += s[15] * wr[15];
            acc[b] = a;
        }
        #pragma unroll
        for (int b = 0; b < 4; ++b)
            __builtin_nontemporal_store(acc[b],
                o + (size_t)(g * 4 + b) * (NPIX / 4));
    }
}

extern "C" void kernel_launch(void* const* d_in, const int* in_sizes, int n_in,
                              void* d_out, int out_size, void* d_ws, size_t ws_size,
                              hipStream_t stream) {
    const float*  positions = (const float*)d_in[0];   // [2048,2]
    const float2* obs       = (const float2*)d_in[1];  // [4096,2]
    const float*  spatial   = (const float*)d_in[2];   // [4096,4096]
    const float*  alpha     = (const float*)d_in[3];   // [4096,16]
    const f32x4*  S4        = (const f32x4*)d_in[4];   // [16,256,256]
    f32x4*        out       = (f32x4*)d_out;           // [2048,256,256]
    float*        inter     = (float*)d_ws;            // [2048,16] scratch

    k_inter<<<BATCH / RPB, 256, 0, stream>>>(positions, obs, spatial, alpha, inter);
    k_opd<<<(NPIX / 1024) * (BATCH / BPB), 256, 0, stream>>>(
        inter, S4, out);
}